// Round 4
// baseline (3323.981 us; speedup 1.0000x reference)
//
#include <hip/hip_runtime.h>
#include <cstdint>
#include <cstddef>

#define BDIM 512   // 8 waves
#define BB   16    // batch rows per block
#define T_   512
#define F_   128
#define H_   128
#define B_   1024
#define OUTL 15
#define ASTR 264   // LDS A row stride in bf16 elems (128 x | 128 h | 8 pad)
#define HSTR 136   // LDS h-buffer row stride
#define NBLK 64    // blocks per role
#define SENT 1000000

typedef __bf16 bf16_t;
typedef __bf16 bf16x8 __attribute__((ext_vector_type(8)));
typedef float  f32x4  __attribute__((ext_vector_type(4)));

__device__ __forceinline__ float sigm(float x) {
    return __builtin_amdgcn_rcpf(1.0f + __expf(-x));
}
__device__ __forceinline__ float tanh_(float x) {
    // overflow-safe: e = exp(-2|x|) in (0,1]
    float ax = __builtin_fabsf(x);
    float e  = __expf(-2.0f * ax);
    float r  = (1.0f - e) * __builtin_amdgcn_rcpf(1.0f + e);
    return __builtin_copysignf(r, x);
}
__device__ __forceinline__ f32x4 mfma16(bf16x8 a, bf16x8 b, f32x4 c) {
    return __builtin_amdgcn_mfma_f32_16x16x32_bf16(a, b, c, 0, 0, 0);
}

__device__ __forceinline__ uint2 pack4(f32x4 v) {
    union { bf16_t h[4]; uint2 u; } P;
    P.h[0] = (bf16_t)v[0]; P.h[1] = (bf16_t)v[1];
    P.h[2] = (bf16_t)v[2]; P.h[3] = (bf16_t)v[3];
    return P.u;
}
__device__ __forceinline__ bf16x8 ld8f(const float* f) {
    f32x4 a = *(const f32x4*)f;
    f32x4 b = *(const f32x4*)(f + 4);
    bf16x8 r;
    r[0] = (bf16_t)a[0]; r[1] = (bf16_t)a[1]; r[2] = (bf16_t)a[2]; r[3] = (bf16_t)a[3];
    r[4] = (bf16_t)b[0]; r[5] = (bf16_t)b[1]; r[6] = (bf16_t)b[2]; r[7] = (bf16_t)b[3];
    return r;
}

// producer->consumer handshake (agent scope: cross-XCD per G16)
__device__ __forceinline__ void publish(int* f, int v) {
    __threadfence();  // agent-scope release fence (L2 writeback on gfx9xx multi-XCD)
    __hip_atomic_store(f, v, __ATOMIC_RELEASE, __HIP_MEMORY_SCOPE_AGENT);
}
__device__ __forceinline__ void spin_ge(int* f, int v) {
    while (__hip_atomic_load(f, __ATOMIC_ACQUIRE, __HIP_MEMORY_SCOPE_AGENT) < v)
        __builtin_amdgcn_s_sleep(4);
}

// 4-gate combined weight fragments for one wave (fp32 source -> bf16 frags).
// lane (c,q): tile nt = gate nt, unit u; frag elem j = W[gate_row][kt*32+q*8+j].
__device__ __forceinline__ void load_frags(
    const float* __restrict__ Wih, const float* __restrict__ Whh,
    const float* __restrict__ bih, const float* __restrict__ bhh,
    int u, int q, bf16x8 wf[4][8], float bias[4])
{
#pragma unroll
    for (int nt = 0; nt < 4; ++nt) {
        int grow = nt * H_ + u;
        bias[nt] = bih[grow] + bhh[grow];
#pragma unroll
        for (int kt = 0; kt < 8; ++kt) {
            if (kt < 4)
                wf[nt][kt] = ld8f(Wih + (size_t)grow * F_ + kt * 32 + q * 8);
            else
                wf[nt][kt] = ld8f(Whh + (size_t)grow * H_ + (kt - 4) * 32 + q * 8);
        }
    }
}

__global__ __launch_bounds__(BDIM) void fused_kernel(
    float* __restrict__ xbuf,
    const float* Wih0, const float* Whh0, const float* bih0, const float* bhh0,
    const float* Wih1, const float* Whh1, const float* bih1, const float* bhh1,
    const float* dWih, const float* dWhh, const float* dbih, const float* dbhh,
    const float* inW, const float* inb, const float* outW, const float* outb,
    const float* attW, const float* attb,
    float* __restrict__ xmean_ws, int* __restrict__ flags,
    float* __restrict__ dout)
{
    __shared__ bf16_t A[2][BB * ASTR];
    __shared__ bf16_t Hb[BB * HSTR];
    __shared__ bf16_t Hb2[BB * HSTR];

    const int tid  = threadIdx.x;
    const int w    = tid >> 6;
    const int lane = tid & 63;
    const int c    = lane & 15;
    const int q    = lane >> 4;
    const bool prod = blockIdx.x < NBLK;
    const int pb   = blockIdx.x & (NBLK - 1);
    const int b0   = pb * BB;
    const int u    = 16 * w + c;
    const int lr   = tid >> 5;          // loader row 0..15
    const int lc4  = (tid & 31) * 4;    // loader col (4 elems)
    int* flg = flags + pb;

    bf16_t* o0 = (bf16_t*)xbuf;                 // out0 transport, in-place in x rows
    const size_t xrow = (size_t)T_ * F_;        // fp32 elems per batch row
    const size_t orow = 2 * (size_t)T_ * F_;    // bf16 slots per batch row
    const size_t myxr = (size_t)(b0 + lr) * xrow;
    const size_t myor = (size_t)(b0 + lr) * orow;

    if (prod) {
        // ---------------- layer 0 producer ----------------
        bf16x8 wf[4][8]; float bias[4];
        load_frags(Wih0, Whh0, bih0, bhh0, u, q, wf, bias);
        float xs[4]  = {0.f, 0.f, 0.f, 0.f};
        float cst[4] = {0.f, 0.f, 0.f, 0.f};

        {   // tile 0 -> LDS, zero h
            f32x4 v0 = *(const f32x4*)(xbuf + myxr + lc4);
            *(uint2*)&A[0][lr * ASTR + lc4] = pack4(v0);
            xs[0] += v0[0]; xs[1] += v0[1]; xs[2] += v0[2]; xs[3] += v0[3];
            uint2 zz; zz.x = 0u; zz.y = 0u;
            *(uint2*)&A[0][lr * ASTR + F_ + lc4] = zz;
        }
        f32x4 vA = *(const f32x4*)(xbuf + myxr + F_ + lc4);   // tile 1 in flight
        __syncthreads();

        for (int t = 0; t < T_; ++t) {
            const int cur = t & 1, nxt = cur ^ 1;
            // publish tiles <= t-2 (stores drained by previous barrier)
            if (tid == 0 && t >= 2 && (t & 1) == 0) publish(flg, t - 1);

            f32x4 vB;
            const bool hx2 = (t + 2 < T_);
            if (hx2) vB = *(const f32x4*)(xbuf + myxr + (size_t)(t + 2) * F_ + lc4);

            // out0 tile t-1: coalesced 8B from LDS h-half of A[cur]
            if (t >= 1) {
                uint2 hv = *(const uint2*)&A[cur][lr * ASTR + F_ + lc4];
                *(uint2*)(o0 + myor + (size_t)(t - 1) * F_ + lc4) = hv;
            }

            f32x4 acc0 = {bias[0], bias[0], bias[0], bias[0]};
            f32x4 acc1 = {bias[1], bias[1], bias[1], bias[1]};
            f32x4 acc2 = {bias[2], bias[2], bias[2], bias[2]};
            f32x4 acc3 = {bias[3], bias[3], bias[3], bias[3]};
            const bf16_t* Ab = &A[cur][0];
#pragma unroll
            for (int kt = 0; kt < 8; ++kt) {
                bf16x8 a = *(const bf16x8*)(Ab + c * ASTR + kt * 32 + q * 8);
                acc0 = mfma16(a, wf[0][kt], acc0);
                acc1 = mfma16(a, wf[1][kt], acc1);
                acc2 = mfma16(a, wf[2][kt], acc2);
                acc3 = mfma16(a, wf[3][kt], acc3);
            }

            if (t + 1 < T_) {   // stage tile t+1 (regs -> LDS)
                *(uint2*)&A[nxt][lr * ASTR + lc4] = pack4(vA);
                xs[0] += vA[0]; xs[1] += vA[1]; xs[2] += vA[2]; xs[3] += vA[3];
            }

#pragma unroll
            for (int j = 0; j < 4; ++j) {
                float i_ = sigm(acc0[j]);
                float f_ = sigm(acc1[j]);
                float g_ = tanh_(acc2[j]);
                float o_ = sigm(acc3[j]);
                float cc = f_ * cst[j] + i_ * g_;
                cst[j] = cc;
                float h_ = o_ * tanh_(cc);
                A[nxt][(q * 4 + j) * ASTR + F_ + u] = (bf16_t)h_;
            }
            __syncthreads();
            vA = vB;
        }

        {   // tail: tile T-1 (h_last sits in A[0] h-half after t=511), xmean
            uint2 hv = *(const uint2*)&A[0][lr * ASTR + F_ + lc4];
            *(uint2*)(o0 + myor + (size_t)(T_ - 1) * F_ + lc4) = hv;
            const float s = 1.0f / (float)T_;
            float* dst = xmean_ws + (size_t)(b0 + lr) * F_ + lc4;
            dst[0] = xs[0] * s; dst[1] = xs[1] * s;
            dst[2] = xs[2] * s; dst[3] = xs[3] * s;
        }
        __syncthreads();                 // drain every wave's stores
        if (tid == 0) publish(flg, SENT);
    } else {
        // ---------------- layer 1 consumer + decoder ----------------
        float cs[4]  = {0.f, 0.f, 0.f, 0.f};
        float cst[4] = {0.f, 0.f, 0.f, 0.f};
        {
            bf16x8 wf[4][8]; float bias[4];
            load_frags(Wih1, Whh1, bih1, bhh1, u, q, wf, bias);

            spin_ge(flg, 2);            // tiles 0,1 ready
            {
                uint2 p0 = *(const uint2*)(o0 + myor + lc4);
                *(uint2*)&A[0][lr * ASTR + lc4] = p0;
                uint2 zz; zz.x = 0u; zz.y = 0u;
                *(uint2*)&A[0][lr * ASTR + F_ + lc4] = zz;
            }
            uint2 pA = *(const uint2*)(o0 + myor + F_ + lc4);   // tile 1
            __syncthreads();

            for (int t = 0; t < T_; ++t) {
                const int cur = t & 1, nxt = cur ^ 1;
                int need = t + 3; if (need > T_) need = T_;
                spin_ge(flg, need);     // tiles <= t+2 ready (acquire per wave)

                uint2 pB;
                const bool hx2 = (t + 2 < T_);
                if (hx2) pB = *(const uint2*)(o0 + myor + (size_t)(t + 2) * F_ + lc4);

                f32x4 acc0 = {bias[0], bias[0], bias[0], bias[0]};
                f32x4 acc1 = {bias[1], bias[1], bias[1], bias[1]};
                f32x4 acc2 = {bias[2], bias[2], bias[2], bias[2]};
                f32x4 acc3 = {bias[3], bias[3], bias[3], bias[3]};
                const bf16_t* Ab = &A[cur][0];
#pragma unroll
                for (int kt = 0; kt < 8; ++kt) {
                    bf16x8 a = *(const bf16x8*)(Ab + c * ASTR + kt * 32 + q * 8);
                    acc0 = mfma16(a, wf[0][kt], acc0);
                    acc1 = mfma16(a, wf[1][kt], acc1);
                    acc2 = mfma16(a, wf[2][kt], acc2);
                    acc3 = mfma16(a, wf[3][kt], acc3);
                }

                if (t + 1 < T_)
                    *(uint2*)&A[nxt][lr * ASTR + lc4] = pA;

#pragma unroll
                for (int j = 0; j < 4; ++j) {
                    float i_ = sigm(acc0[j]);
                    float f_ = sigm(acc1[j]);
                    float g_ = tanh_(acc2[j]);
                    float o_ = sigm(acc3[j]);
                    float cc = f_ * cst[j] + i_ * g_;
                    cst[j] = cc;
                    float h_ = o_ * tanh_(cc);
                    cs[j] += h_;
                    A[nxt][(q * 4 + j) * ASTR + F_ + u] = (bf16_t)h_;
                }
                __syncthreads();
                pA = pB;
            }
        }
        // h_last: A[0] h-half (t=511 wrote nxt=0). cst = c_last (fp32, in regs).

        {   // ctx -> Hb2 (bf16, row x col layout)
            const float s = 1.0f / (float)T_;
#pragma unroll
            for (int j = 0; j < 4; ++j)
                Hb2[(q * 4 + j) * HSTR + u] = (bf16_t)(cs[j] * s);
        }
        spin_ge(flg, SENT);             // xmean published
        {   // xmean -> Hb
            f32x4 xm = *(const f32x4*)(xmean_ws + (size_t)(b0 + lr) * F_ + lc4);
            Hb[lr * HSTR + lc4 + 0] = (bf16_t)xm[0];
            Hb[lr * HSTR + lc4 + 1] = (bf16_t)xm[1];
            Hb[lr * HSTR + lc4 + 2] = (bf16_t)xm[2];
            Hb[lr * HSTR + lc4 + 3] = (bf16_t)xm[3];
        }

        // decoder weights (loaded after enc frags die -> regs reused)
        bf16x8 wd[4][8]; float biasd[4];
        load_frags(dWih, dWhh, dbih, dbhh, u, q, wd, biasd);
        bf16x8 wa[4], wo[4];
#pragma unroll
        for (int kt = 0; kt < 4; ++kt) {
            wa[kt] = ld8f(attW + (size_t)u * 256 + kt * 32 + q * 8);
            wo[kt] = ld8f(outW + (size_t)u * H_ + kt * 32 + q * 8);
        }
        const float outb_f = outb[u];
        const float inb_f  = inb[u];
        const float attb_f = attb[u];
        __syncthreads();                // Hb/Hb2 visible to all waves

        bf16_t* Ad = &A[0][0];          // h-half already holds h_last
        {   // din = xmean @ inW^T + inb -> Ad x-half
            f32x4 accd = {inb_f, inb_f, inb_f, inb_f};
#pragma unroll
            for (int kt = 0; kt < 4; ++kt) {
                bf16x8 a  = *(const bf16x8*)(Hb + c * HSTR + kt * 32 + q * 8);
                bf16x8 bw = ld8f(inW + (size_t)u * F_ + kt * 32 + q * 8);
                accd = mfma16(a, bw, accd);
            }
#pragma unroll
            for (int j = 0; j < 4; ++j)
                Ad[(q * 4 + j) * ASTR + u] = (bf16_t)accd[j];
        }
        f32x4 ctxp;
        {   // ctxproj = ctx @ Wa2^T + attn_b (step-invariant)
            f32x4 acca = {attb_f, attb_f, attb_f, attb_f};
#pragma unroll
            for (int kt = 0; kt < 4; ++kt) {
                bf16x8 a  = *(const bf16x8*)(Hb2 + c * HSTR + kt * 32 + q * 8);
                bf16x8 bw = ld8f(attW + (size_t)u * 256 + 128 + kt * 32 + q * 8);
                acca = mfma16(a, bw, acca);
            }
            ctxp = acca;
        }
        __syncthreads();

        for (int st = 0; st < OUTL; ++st) {
            f32x4 acc0 = {biasd[0], biasd[0], biasd[0], biasd[0]};
            f32x4 acc1 = {biasd[1], biasd[1], biasd[1], biasd[1]};
            f32x4 acc2 = {biasd[2], biasd[2], biasd[2], biasd[2]};
            f32x4 acc3 = {biasd[3], biasd[3], biasd[3], biasd[3]};
#pragma unroll
            for (int kt = 0; kt < 8; ++kt) {
                bf16x8 a = *(const bf16x8*)(Ad + c * ASTR + kt * 32 + q * 8);
                acc0 = mfma16(a, wd[0][kt], acc0);
                acc1 = mfma16(a, wd[1][kt], acc1);
                acc2 = mfma16(a, wd[2][kt], acc2);
                acc3 = mfma16(a, wd[3][kt], acc3);
            }
#pragma unroll
            for (int j = 0; j < 4; ++j) {
                float i_ = sigm(acc0[j]);
                float f_ = sigm(acc1[j]);
                float g_ = tanh_(acc2[j]);
                float o_ = sigm(acc3[j]);
                float cc = f_ * cst[j] + i_ * g_;
                cst[j] = cc;
                float h_ = o_ * tanh_(cc);
                Hb[(q * 4 + j) * HSTR + u] = (bf16_t)h_;
            }
            __syncthreads();

            f32x4 acch = ctxp;          // h2 = h + h@Wa1^T + ctxproj
#pragma unroll
            for (int kt = 0; kt < 4; ++kt) {
                bf16x8 a = *(const bf16x8*)(Hb + c * HSTR + kt * 32 + q * 8);
                acch = mfma16(a, wa[kt], acch);
            }
#pragma unroll
            for (int j = 0; j < 4; ++j) {
                int r = q * 4 + j;
                float h2 = acch[j] + (float)Hb[r * HSTR + u];
                Hb2[r * HSTR + u]    = (bf16_t)h2;
                Ad[r * ASTR + F_ + u] = (bf16_t)h2;   // next-step recurrent h
            }
            __syncthreads();

            f32x4 acco = {outb_f, outb_f, outb_f, outb_f};  // out = h2 @ outW^T + outb
#pragma unroll
            for (int kt = 0; kt < 4; ++kt) {
                bf16x8 a = *(const bf16x8*)(Hb2 + c * HSTR + kt * 32 + q * 8);
                acco = mfma16(a, wo[kt], acco);
            }
#pragma unroll
            for (int j = 0; j < 4; ++j) {
                int r = q * 4 + j;
                float ov = acco[j];
                dout[((size_t)(b0 + r) * OUTL + st) * F_ + u] = ov;
                Ad[r * ASTR + u] = (bf16_t)ov;        // next din
            }
            __syncthreads();
        }
    }
}

extern "C" void kernel_launch(void* const* d_in, const int* in_sizes, int n_in,
                              void* d_out, int out_size, void* d_ws, size_t ws_size,
                              hipStream_t stream) {
    (void)in_sizes; (void)n_in; (void)out_size; (void)ws_size;

    float* x = (float*)d_in[0];
    const float* Wih0 = (const float*)d_in[1];
    const float* Whh0 = (const float*)d_in[2];
    const float* bih0 = (const float*)d_in[3];
    const float* bhh0 = (const float*)d_in[4];
    const float* Wih1 = (const float*)d_in[5];
    const float* Whh1 = (const float*)d_in[6];
    const float* bih1 = (const float*)d_in[7];
    const float* bhh1 = (const float*)d_in[8];
    const float* dWih = (const float*)d_in[9];
    const float* dWhh = (const float*)d_in[10];
    const float* dbih = (const float*)d_in[11];
    const float* dbhh = (const float*)d_in[12];
    const float* inW  = (const float*)d_in[13];
    const float* inb  = (const float*)d_in[14];
    const float* outW = (const float*)d_in[15];
    const float* outb = (const float*)d_in[16];
    const float* attW = (const float*)d_in[17];
    const float* attb = (const float*)d_in[18];

    int*   flags = (int*)d_ws;                       // 64 ints (poisoned -> negative, OK)
    float* xmean = (float*)((char*)d_ws + 1024);     // B*F fp32

    fused_kernel<<<2 * NBLK, BDIM, 0, stream>>>(
        x, Wih0, Whh0, bih0, bhh0, Wih1, Whh1, bih1, bhh1,
        dWih, dWhh, dbih, dbhh, inW, inb, outW, outb, attW, attb,
        xmean, flags, (float*)d_out);
}